// Round 11
// baseline (2762.435 us; speedup 1.0000x reference)
//
#include <hip/hip_runtime.h>
#include <hip/hip_bf16.h>
#include <math.h>

// ---------------------------------------------------------------------------
// MoE block: router + grouped-expert SwiGLU + shared SwiGLU MLP.
// Round 11: reads-at-phase-start with FULL fragment double-buffering
// (aE/aO + bE/bO = 96 VGPR): every ds_read group drains under a full MFMA
// phase before its consuming MFMA; read bursts rebalanced 4/8/8/4/4/8/8/4.
// B staging pointers collapsed to one base + uniform offsets (VGPR budget).
// ---------------------------------------------------------------------------

typedef __bf16 bf16_t;
typedef __bf16 bf16x8 __attribute__((ext_vector_type(8)));
typedef float  f32x4  __attribute__((ext_vector_type(4)));

constexpr int NTOK = 8192;          // B*S
constexpr int D    = 2048;
constexpr int E    = 32;
constexpr int I    = 1024;
constexpr int TK   = 8;             // TOP_K
constexpr int NK   = NTOK * TK;     // 65536 slots
constexpr int TM   = 256;           // GEMM row tile
constexpr int MAX_TILES = E + NK / TM;   // 288 worst-case row tiles (div by 8)
constexpr float RSCALE = 2.5f;

#define GL16(g, l) __builtin_amdgcn_global_load_lds( \
    (const __attribute__((address_space(1))) void*)(g), \
    (__attribute__((address_space(3))) void*)(l), 16, 0, 0)

// ------------------------------- utilities --------------------------------

__global__ __launch_bounds__(64) void k_zero_meta(int* counts, int* cursors, int* ntl) {
    int t = threadIdx.x;
    if (t < E) { counts[t] = 0; cursors[t] = 0; }
    if (t == 0) *ntl = 0;
}

__global__ __launch_bounds__(64) void k_sentinel(float* out) {
    if (threadIdx.x == 0) out[0] = 12345.0f;   // signals ws_size too small
}

// f32 -> bf16, 8 elems/thread
__global__ __launch_bounds__(256) void k_convert_x(const float* __restrict__ src,
                                                   bf16_t* __restrict__ dst, int n8) {
    int i = blockIdx.x * 256 + threadIdx.x;
    if (i >= n8) return;
    const float4* s = (const float4*)src;
    float4 a = s[(size_t)i * 2], b = s[(size_t)i * 2 + 1];
    bf16_t t[8] = {(bf16_t)a.x, (bf16_t)a.y, (bf16_t)a.z, (bf16_t)a.w,
                   (bf16_t)b.x, (bf16_t)b.y, (bf16_t)b.z, (bf16_t)b.w};
    *(uint4*)(dst + (size_t)i * 8) = *(const uint4*)t;
}

// batched transpose+convert: src [b][R][C] f32 -> dst [b][rc(C)][R] bf16
// MODE 0: rc=c | 1: gate/up interleave (c<I ? 2c : 2(c-I)+1) | 2: rc=2c | 3: rc=2c+1
template <int MODE>
__global__ __launch_bounds__(256) void k_transpose(const float* __restrict__ src,
                                                   bf16_t* __restrict__ dst,
                                                   int R, int C,
                                                   size_t srcMat, size_t dstMat) {
    __shared__ float t[32][33];
    int b = blockIdx.z;
    const float* s = src + (size_t)b * srcMat;
    bf16_t* d = dst + (size_t)b * dstMat;
    int c0 = blockIdx.x * 32, r0 = blockIdx.y * 32;
    int tx = threadIdx.x, ty = threadIdx.y;    // 32 x 8
#pragma unroll
    for (int yy = 0; yy < 4; yy++)
        t[ty + yy * 8][tx] = s[(size_t)(r0 + ty + yy * 8) * C + c0 + tx];
    __syncthreads();
#pragma unroll
    for (int yy = 0; yy < 4; yy++) {
        int c = c0 + ty + yy * 8;
        int rc = (MODE == 0) ? c
               : (MODE == 1) ? ((c < I) ? 2 * c : 2 * (c - I) + 1)
               : (MODE == 2) ? 2 * c : 2 * c + 1;
        d[(size_t)rc * R + r0 + tx] = (bf16_t)t[tx][ty + yy * 8];
    }
}

// ------------------------------- router -----------------------------------

__global__ __launch_bounds__(256) void k_router(const float* __restrict__ x,
                                                const float* __restrict__ gw,
                                                const float* __restrict__ eb,
                                                float* __restrict__ out_idx,
                                                float* __restrict__ out_scores,
                                                float* __restrict__ topk_w,
                                                int* __restrict__ tok_expert,
                                                int* __restrict__ counts) {
    int t = blockIdx.x;
    int tid = threadIdx.x;
    int e = tid & 31, part = tid >> 5;         // 8 parts x 256 d each
    const float* xr = x + (size_t)t * D;
    float partial = 0.f;
    int d0 = part * 256;
    for (int d = d0; d < d0 + 256; d++)
        partial += xr[d] * gw[(size_t)d * E + e];

    __shared__ float red[8][32];
    __shared__ float sc[32], sfr[32];
    red[part][e] = partial;
    __syncthreads();
    if (tid < 32) {
        float l = 0.f;
#pragma unroll
        for (int p = 0; p < 8; p++) l += red[p][tid];
        float s = 1.f / (1.f + expf(-l));
        sc[tid] = s;
        sfr[tid] = s + eb[tid];
        out_scores[(size_t)t * E + tid] = s;
    }
    __syncthreads();
    if (tid == 0) {
        float gs[8];
#pragma unroll
        for (int g = 0; g < 8; g++) {
            float m1 = -1e30f, m2 = -1e30f;
#pragma unroll
            for (int i = 0; i < 4; i++) {
                float v = sfr[g * 4 + i];
                if (v > m1) { m2 = m1; m1 = v; } else if (v > m2) m2 = v;
            }
            gs[g] = m1 + m2;
        }
        bool gsel[8] = {false, false, false, false, false, false, false, false};
        for (int it = 0; it < 4; it++) {
            int bi = -1; float bv = -1e30f;
            for (int g = 0; g < 8; g++)
                if (!gsel[g] && gs[g] > bv) { bv = gs[g]; bi = g; }
            gsel[bi] = true;
        }
        float masked[32];
        for (int i = 0; i < 32; i++) masked[i] = gsel[i >> 2] ? sfr[i] : -1e30f;
        int idx[TK]; float w[TK]; float wsum = 0.f;
        for (int k = 0; k < TK; k++) {
            int bi = 0; float bv = -1e30f;
            for (int i = 0; i < 32; i++)
                if (masked[i] > bv) { bv = masked[i]; bi = i; }
            masked[bi] = -1e30f;
            idx[k] = bi; w[k] = sc[bi]; wsum += w[k];
        }
        float inv = RSCALE / (wsum + 1e-20f);
        for (int k = 0; k < TK; k++) {
            out_idx[(size_t)t * TK + k] = (float)idx[k];
            topk_w[(size_t)t * TK + k] = w[k] * inv;
            tok_expert[(size_t)t * TK + k] = idx[k];
            atomicAdd(&counts[idx[k]], 1);
        }
    }
}

__global__ __launch_bounds__(64) void k_offsets(const int* __restrict__ counts,
                                                int* __restrict__ offs,
                                                int4* __restrict__ ttbl,
                                                int* __restrict__ ntl) {
    if (threadIdx.x != 0) return;
    int off = 0, nt = 0;
    for (int e = 0; e < E; e++) {
        offs[e] = off;
        int c = counts[e];
        for (int r = 0; r < c; r += TM) {
            ttbl[nt] = make_int4(off + r, min(TM, c - r), e, 0);
            nt++;
        }
        off += c;
    }
    offs[E] = off;
    *ntl = nt;
}

__global__ __launch_bounds__(256) void k_scatter(const int* __restrict__ tok_expert,
                                                 const int* __restrict__ offs,
                                                 int* __restrict__ cursors,
                                                 int* __restrict__ slot_token,
                                                 int* __restrict__ slot_inv) {
    int i = blockIdx.x * 256 + threadIdx.x;
    if (i >= NK) return;
    int e = tok_expert[i];
    int pos = offs[e] + atomicAdd(&cursors[e], 1);
    slot_token[pos] = i >> 3;   // TK = 8
    slot_inv[i] = pos;
}

// --------------------- 256x256 8-phase pipelined GEMM ----------------------
// 512 threads = 8 waves (2M x 4N); per-wave C = 128 rows x 64 cols.
// LDS 128 KiB: 2 buffers x (A[256][64] + B[256][64]) bf16, XOR-swizzled.
//
// ROUND-11 SCHEDULE — reads at PHASE START, full fragment double-buffer:
//   sets: aE/aO (mh0/mh1 data, 32 VGPR each), bE/bO (nh0/nh1, 16 each).
//   phase:  reads(dst)        MFMA(src)          stage         #reads
//   P1:     bO<-buf0.nh1      (aE,bE)->acc[0][0] SA2(1,1,k1)    4
//   P2:     aO<-buf0.mh1      (aE,bO)->acc[0][1] SA2(0,0,k2)    8
//   P3:     aE<-buf1.mh0      (aO,bE)->acc[1][0] SB(0,0,k2)     8
//   P4:     bE<-buf1.nh0      (aO,bO)->acc[1][1] SB(0,1,k2)     4
//   P5:     bO<-buf1.nh1      (aE,bE)->acc[0][0] SA2(0,1,k2)    4
//   P6:     aO<-buf1.mh1      (aE,bO)->acc[0][1] SA2(1,0,k3)    8
//   P7:     aE<-buf0'.mh0     (aO,bE)->acc[1][0] SB(1,0,k3)     8
//   P8:     bE<-buf0'.nh0     (aO,bO)->acc[1][1] SB(1,1,k3)     4
// Invariants (verified):
//  - every MFMA's operands were read >= 1 full phase earlier (621-cyc drain);
//  - read dst set != this phase's MFMA src set (no WAR, no rename pressure);
//  - stage@q is >= 2 phases after its region's last read-issue, whose lgkm
//    drain happened before the intervening phase's MFMA (hard WAR-safe);
//  - vmcnt(4) every phase end => ops@q published at end q+2; all stage->read
//    publication deadlines hold (min slack 1 phase);
//  - loop never drains vmcnt to 0 (T4).

#define SCB() __builtin_amdgcn_sched_barrier(0)

#define PEND() do { asm volatile("s_waitcnt vmcnt(4)" ::: "memory"); \
    __builtin_amdgcn_s_barrier(); SCB(); } while (0)

// A stage unit (b, rnd): rows rnd*64..+63 (h0) and 128+rnd*64..+63 (h1)
#define SA2(b, rnd, k0) do { \
    GL16(gA[0][rnd] + (k0), smb + (b) * 65536 + (rnd) * 8192 + w * 1024); \
    GL16(gA[1][rnd] + (k0), smb + (b) * 65536 + 16384 + (rnd) * 8192 + w * 1024); } while (0)

// B stage unit (b, h): cols h*128..+127 (single base + uniform row offsets)
#define SB(b, h, k0) do { \
    GL16(gBb + (size_t)((h) * 128) * K + (k0), smb + (b) * 65536 + 32768 + (h) * 16384 + w * 1024); \
    GL16(gBb + (size_t)((h) * 128 + 64) * K + (k0), smb + (b) * 65536 + 32768 + (h) * 16384 + 8192 + w * 1024); } while (0)

#define LDA(dst, b, mh) do { _Pragma("unroll") for (int m_ = 0; m_ < 4; m_++) { \
    dst[m_][0] = *(const bf16x8*)(smb + (b) * 65536 + wm * 16384 + (mh) * 8192 + m_ * 2048 + lofs0); \
    dst[m_][1] = *(const bf16x8*)(smb + (b) * 65536 + wm * 16384 + (mh) * 8192 + m_ * 2048 + lofs1); } } while (0)

#define LDB(dst, b, nh) do { _Pragma("unroll") for (int n_ = 0; n_ < 2; n_++) { \
    dst[n_][0] = *(const bf16x8*)(smb + (b) * 65536 + 32768 + wn * 8192 + (nh) * 4096 + n_ * 2048 + lofs0); \
    dst[n_][1] = *(const bf16x8*)(smb + (b) * 65536 + 32768 + wn * 8192 + (nh) * 4096 + n_ * 2048 + lofs1); } } while (0)

#define MMA(av, bv, MH, NH) do { \
    __builtin_amdgcn_s_setprio(1); \
    _Pragma("unroll") for (int m_ = 0; m_ < 4; m_++) \
    _Pragma("unroll") for (int n_ = 0; n_ < 2; n_++) { \
    acc[(MH) * 4 + m_][(NH) * 2 + n_] = __builtin_amdgcn_mfma_f32_16x16x32_bf16( \
        av[m_][0], bv[n_][0], acc[(MH) * 4 + m_][(NH) * 2 + n_], 0, 0, 0); \
    acc[(MH) * 4 + m_][(NH) * 2 + n_] = __builtin_amdgcn_mfma_f32_16x16x32_bf16( \
        av[m_][1], bv[n_][1], acc[(MH) * 4 + m_][(NH) * 2 + n_], 0, 0, 0); } \
    __builtin_amdgcn_s_setprio(0); } while (0)

template <bool EXPERT, bool GATHER, int EPI>
__global__ __launch_bounds__(512, 2) void k_mm8(const bf16_t* __restrict__ A,
                                                const bf16_t* __restrict__ Bt,
                                                int K, size_t estride,
                                                const int* __restrict__ slot_token,
                                                const int4* __restrict__ ttbl,
                                                const int* __restrict__ ntl,
                                                void* __restrict__ C, int ldc) {
    // XCD-chunked swizzle (grid.y divisible by 8)
    int L = (int)blockIdx.y * 8 + (int)blockIdx.x;
    int xcd = L & 7, k = L >> 3;
    int per = (int)gridDim.y >> 3;
    int ty = xcd * per + (k >> 3);
    int tx = k & 7;

    int base_slot, rows, e;
    if (EXPERT) {
        if (ty >= *ntl) return;
        int4 tt = ttbl[ty];
        base_slot = tt.x; rows = tt.y; e = tt.z;
    } else {
        base_slot = ty * TM; rows = TM; e = 0;
    }
    int c0 = tx * 256;
    const bf16_t* Bw = Bt + (size_t)e * estride + (size_t)c0 * K;

    extern __shared__ char smb[];   // 128 KiB: [2][A 32K | B 32K]

    int tid = threadIdx.x, lane = tid & 63, w = tid >> 6;
    int wm = w >> 2, wn = w & 3;
    int lr = lane & 15, hi = lane >> 4;
    int rx = lr & 7;
    // swizzled ds_read lane offsets (16B chunk cb in [0,8), cb ^= row&7)
    int lofs0 = lr * 128 + ((hi ^ rx) << 4);
    int lofs1 = lr * 128 + (((4 + hi) ^ rx) << 4);

    // staging: row = h*128 + rnd*64 + tid/8; global chunk = (tid&7) ^ (row&7)
    int srow = tid >> 3;
    int cbg = (tid & 7) ^ (srow & 7);
    const bf16_t* gA[2][2];
#pragma unroll
    for (int h = 0; h < 2; h++)
#pragma unroll
        for (int rnd = 0; rnd < 2; rnd++) {
            int r = h * 128 + rnd * 64 + srow;
            int ar = min(r, rows - 1);
            int tok = GATHER ? slot_token[base_slot + ar] : (base_slot + ar);
            gA[h][rnd] = A + (size_t)tok * K + cbg * 8;
        }
    const bf16_t* gBb = Bw + (size_t)srow * K + cbg * 8;

    f32x4 acc[8][4] = {};
    bf16x8 aE[4][2], aO[4][2], bE[2][2], bO[2][2];

    // prologue: buf0 all 4 units (t=0), buf1 {A.rnd0, B.h0, B.h1} (t=1;
    // buf1.A.rnd1 staged at P1 published P3 < its P6 read). Drain, publish,
    // then pre-read the "P7/P8" fragments feeding P1/P3.
    SA2(0, 0, 0); SA2(0, 1, 0);
    SB(0, 0, 0); SB(0, 1, 0);
    SA2(1, 0, 64);
    SB(1, 0, 64); SB(1, 1, 64);
    asm volatile("s_waitcnt vmcnt(0)" ::: "memory");
    __builtin_amdgcn_s_barrier();
    SCB();
    LDA(aE, 0, 0); LDB(bE, 0, 0);

    int nt = K >> 6;                 // K/64, even (16 or 32)
    for (int kt = 0; kt < nt; kt += 2) {
        int k1 = (kt + 1) << 6;
        int k2 = (kt + 2 < nt) ? (kt + 2) << 6 : 0;   // wrapped garbage, never consumed
        int k3 = (kt + 3 < nt) ? (kt + 3) << 6 : 0;
        // P1
        LDB(bO, 0, 1); SA2(1, 1, k1); SCB();
        MMA(aE, bE, 0, 0); PEND();
        // P2
        LDA(aO, 0, 1); SA2(0, 0, k2); SCB();
        MMA(aE, bO, 0, 1); PEND();
        // P3
        LDA(aE, 1, 0); SB(0, 0, k2); SCB();
        MMA(aO, bE, 1, 0); PEND();
        // P4
        LDB(bE, 1, 0); SB(0, 1, k2); SCB();
        MMA(aO, bO, 1, 1); PEND();
        // P5
        LDB(bO, 1, 1); SA2(0, 1, k2); SCB();
        MMA(aE, bE, 0, 0); PEND();
        // P6
        LDA(aO, 1, 1); SA2(1, 0, k3); SCB();
        MMA(aE, bO, 0, 1); PEND();
        // P7
        LDA(aE, 0, 0); SB(1, 0, k3); SCB();
        MMA(aO, bE, 1, 0); PEND();
        // P8
        LDB(bE, 0, 0); SB(1, 1, k3); SCB();
        MMA(aO, bO, 1, 1); PEND();
    }

    // epilogue: C row r = wm*128 + mi*16 + hi*4 + j, col = c0 + wn*64 + f*16 + lr
#pragma unroll
    for (int mi = 0; mi < 8; mi++) {
#pragma unroll
        for (int j = 0; j < 4; j++) {
            int r = wm * 128 + mi * 16 + hi * 4 + j;
            bool valid = !EXPERT || (r < rows);
            size_t orow = (size_t)base_slot + r;
#pragma unroll
            for (int f = 0; f < 4; f++) {
                float v = acc[mi][f][j];
                int c = c0 + wn * 64 + f * 16 + lr;
                if (EPI == 0) {
                    float o = __shfl_xor(v, 1);
                    float g = (lane & 1) ? o : v;
                    float u = (lane & 1) ? v : o;
                    float sv = g / (1.f + __expf(-g)) * u;
                    if (valid && !(lane & 1))
                        ((bf16_t*)C)[orow * ldc + (c >> 1)] = (bf16_t)sv;
                } else if (EPI == 1) {
                    float o = __shfl_xor(v, 1);
                    if (valid && !(lane & 1)) {
                        bf16_t pr[2] = {(bf16_t)v, (bf16_t)o};
                        *(unsigned int*)((bf16_t*)C + orow * ldc + c) = *(unsigned int*)pr;
                    }
                } else {
                    if (valid) ((float*)C)[orow * ldc + c] = v;
                }
            }
        }
    }
}

// ------------------------------- finalize ----------------------------------
// out[tok][d] += sum_k w_k * outS[pos(tok,k)][d]   (out already = shared MLP)

__global__ __launch_bounds__(256) void k_finalize(const bf16_t* __restrict__ outS,
                                                  const int* __restrict__ slot_inv,
                                                  const float* __restrict__ tkw,
                                                  float* __restrict__ out) {
    int tok = blockIdx.x, tid = threadIdx.x;
    __shared__ int sp[TK];
    __shared__ float swt[TK];
    if (tid < TK) {
        sp[tid] = slot_inv[tok * TK + tid];
        swt[tid] = tkw[tok * TK + tid];
    }
    __syncthreads();
    int c = tid * 8;                 // 2048 / 256
    float* op = out + (size_t)tok * D + c;
    float acc[8];
    float4 o0 = *(float4*)op, o1 = *(float4*)(op + 4);
    acc[0] = o0.x; acc[1] = o0.y; acc[2] = o0.z; acc[3] = o0.w;
    acc[4] = o1.x; acc[5] = o1.y; acc[6] = o1.z; acc[7] = o1.w;
#pragma unroll
    for (int k = 0; k < TK; k++) {
        bf16x8 v = *(const bf16x8*)(outS + (size_t)sp[k] * D + c);
        float w = swt[k];
#pragma unroll
        for (int j = 0; j < 8; j++) acc[j] += w * (float)v[j];
    }
    o0 = make_float4(acc[0], acc[1], acc[2], acc[3]);
    o1 = make_float4(acc[4], acc[5], acc[6], acc[7]);
    *(float4*)op = o0;
    *(float4*)(op + 4) = o1;
}

// ------------------------------- launcher ---------------------------------

extern "C" void kernel_launch(void* const* d_in, const int* in_sizes, int n_in,
                              void* d_out, int out_size, void* d_ws, size_t ws_size,
                              hipStream_t stream) {
    const float* x  = (const float*)d_in[0];
    const float* gw = (const float*)d_in[1];
    const float* eb = (const float*)d_in[2];
    const float* gu = (const float*)d_in[3];
    const float* dn = (const float*)d_in[4];
    const float* sg = (const float*)d_in[5];
    const float* su = (const float*)d_in[6];
    const float* sd = (const float*)d_in[7];

    float* out        = (float*)d_out;
    float* out_idx    = out + (size_t)NTOK * D;
    float* out_scores = out_idx + (size_t)NTOK * TK;

    char* w = (char*)d_ws;
    auto alloc = [&](size_t bytes) {
        char* p = w;
        w += (bytes + 255) & ~(size_t)255;
        return p;
    };
    bf16_t* xb      = (bf16_t*)alloc((size_t)NTOK * D * 2);
    bf16_t* gut     = (bf16_t*)alloc((size_t)E * 2 * I * D * 2);   // [E][2I][D] interleaved
    bf16_t* dnt     = (bf16_t*)alloc((size_t)E * D * I * 2);       // [E][D][I]
    bf16_t* sh1t    = (bf16_t*)alloc((size_t)2 * I * D * 2);       // [2I][D] interleaved
    bf16_t* sdt     = (bf16_t*)alloc((size_t)D * I * 2);           // [D][I]
    bf16_t* inter   = (bf16_t*)alloc((size_t)NK * I * 2);
    bf16_t* inter_s = (bf16_t*)alloc((size_t)NTOK * I * 2);
    float*  tkw     = (float*)alloc((size_t)NK * 4);
    int*    tke     = (int*)alloc((size_t)NK * 4);
    int*    stok    = (int*)alloc((size_t)NK * 4);
    int*    sinv    = (int*)alloc((size_t)NK * 4);
    int*    counts  = (int*)alloc(E * 4);
    int*    offs    = (int*)alloc((E + 1) * 4);
    int*    curs    = (int*)alloc(E * 4);
    int4*   ttbl    = (int4*)alloc(MAX_TILES * 16);
    int*    ntl     = (int*)alloc(4);
    // outS[NK][D] bf16 (256MB) aliases gut (256MB): gut is dead after expert gemm1
    bf16_t* outS    = gut;

    if ((size_t)(w - (char*)d_ws) > ws_size) {
        k_sentinel<<<1, 64, 0, stream>>>(out);
        return;
    }

    k_zero_meta<<<1, 64, 0, stream>>>(counts, curs, ntl);
    k_convert_x<<<(NTOK * D / 8 + 255) / 256, 256, 0, stream>>>(x, xb, NTOK * D / 8);

    // weight reshapes
    k_transpose<1><<<dim3(2 * I / 32, D / 32, E), dim3(32, 8), 0, stream>>>(
        gu, gut, D, 2 * I, (size_t)D * 2 * I, (size_t)D * 2 * I);
    k_transpose<0><<<dim3(D / 32, I / 32, E), dim3(32, 8), 0, stream>>>(
        dn, dnt, I, D, (size_t)I * D, (size_t)I * D);
    k_transpose<2><<<dim3(I / 32, D / 32, 1), dim3(32, 8), 0, stream>>>(
        sg, sh1t, D, I, 0, 0);
    k_transpose<3><<<dim3(I / 32, D / 32, 1), dim3(32, 8), 0, stream>>>(
        su, sh1t, D, I, 0, 0);
    k_transpose<0><<<dim3(D / 32, I / 32, 1), dim3(32, 8), 0, stream>>>(
        sd, sdt, I, D, 0, 0);

    // routing
    k_router<<<NTOK, 256, 0, stream>>>(x, gw, eb, out_idx, out_scores, tkw, tke, counts);
    k_offsets<<<1, 64, 0, stream>>>(counts, offs, ttbl, ntl);
    k_scatter<<<NK / 256, 256, 0, stream>>>(tke, offs, curs, stok, sinv);

    constexpr size_t SMEM = 131072;
    // expert path (gemm1 must finish before outS overwrites gut)
    k_mm8<true, true, 0><<<dim3(8, MAX_TILES), 512, SMEM, stream>>>(
        xb, gut, D, (size_t)2 * I * D, stok, ttbl, ntl, inter, I);
    k_mm8<true, false, 1><<<dim3(8, MAX_TILES), 512, SMEM, stream>>>(
        inter, dnt, I, (size_t)D * I, stok, ttbl, ntl, outS, D);

    // shared path
    k_mm8<false, false, 0><<<dim3(8, NTOK / TM), 512, SMEM, stream>>>(
        xb, sh1t, D, 0, nullptr, nullptr, nullptr, inter_s, I);
    k_mm8<false, false, 2><<<dim3(8, NTOK / TM), 512, SMEM, stream>>>(
        inter_s, sdt, I, 0, nullptr, nullptr, nullptr, out, D);

    // combine
    k_finalize<<<NTOK, 256, 0, stream>>>(outS, sinv, tkw, out);
}

// Round 12
// 1808.877 us; speedup vs baseline: 1.5272x; 1.5272x over previous
//
#include <hip/hip_runtime.h>
#include <hip/hip_bf16.h>
#include <math.h>

// ---------------------------------------------------------------------------
// MoE block: router + grouped-expert SwiGLU + shared SwiGLU MLP.
// Round 12: R10 structure (single aF set, 124 VGPR — R11's full double-buffer
// spilled) + WAR-safe refill interleave: each aF[m] is refilled by ds_reads
// placed immediately after its last consuming MFMA, pinned with
// sched_group_barrier so 6/8 refill reads drain UNDER the MFMA cluster.
// ---------------------------------------------------------------------------

typedef __bf16 bf16_t;
typedef __bf16 bf16x8 __attribute__((ext_vector_type(8)));
typedef float  f32x4  __attribute__((ext_vector_type(4)));

constexpr int NTOK = 8192;          // B*S
constexpr int D    = 2048;
constexpr int E    = 32;
constexpr int I    = 1024;
constexpr int TK   = 8;             // TOP_K
constexpr int NK   = NTOK * TK;     // 65536 slots
constexpr int TM   = 256;           // GEMM row tile
constexpr int MAX_TILES = E + NK / TM;   // 288 worst-case row tiles (div by 8)
constexpr float RSCALE = 2.5f;

#define GL16(g, l) __builtin_amdgcn_global_load_lds( \
    (const __attribute__((address_space(1))) void*)(g), \
    (__attribute__((address_space(3))) void*)(l), 16, 0, 0)

// ------------------------------- utilities --------------------------------

__global__ __launch_bounds__(64) void k_zero_meta(int* counts, int* cursors, int* ntl) {
    int t = threadIdx.x;
    if (t < E) { counts[t] = 0; cursors[t] = 0; }
    if (t == 0) *ntl = 0;
}

__global__ __launch_bounds__(64) void k_sentinel(float* out) {
    if (threadIdx.x == 0) out[0] = 12345.0f;   // signals ws_size too small
}

// f32 -> bf16, 8 elems/thread
__global__ __launch_bounds__(256) void k_convert_x(const float* __restrict__ src,
                                                   bf16_t* __restrict__ dst, int n8) {
    int i = blockIdx.x * 256 + threadIdx.x;
    if (i >= n8) return;
    const float4* s = (const float4*)src;
    float4 a = s[(size_t)i * 2], b = s[(size_t)i * 2 + 1];
    bf16_t t[8] = {(bf16_t)a.x, (bf16_t)a.y, (bf16_t)a.z, (bf16_t)a.w,
                   (bf16_t)b.x, (bf16_t)b.y, (bf16_t)b.z, (bf16_t)b.w};
    *(uint4*)(dst + (size_t)i * 8) = *(const uint4*)t;
}

// batched transpose+convert: src [b][R][C] f32 -> dst [b][rc(C)][R] bf16
// MODE 0: rc=c | 1: gate/up interleave (c<I ? 2c : 2(c-I)+1) | 2: rc=2c | 3: rc=2c+1
template <int MODE>
__global__ __launch_bounds__(256) void k_transpose(const float* __restrict__ src,
                                                   bf16_t* __restrict__ dst,
                                                   int R, int C,
                                                   size_t srcMat, size_t dstMat) {
    __shared__ float t[32][33];
    int b = blockIdx.z;
    const float* s = src + (size_t)b * srcMat;
    bf16_t* d = dst + (size_t)b * dstMat;
    int c0 = blockIdx.x * 32, r0 = blockIdx.y * 32;
    int tx = threadIdx.x, ty = threadIdx.y;    // 32 x 8
#pragma unroll
    for (int yy = 0; yy < 4; yy++)
        t[ty + yy * 8][tx] = s[(size_t)(r0 + ty + yy * 8) * C + c0 + tx];
    __syncthreads();
#pragma unroll
    for (int yy = 0; yy < 4; yy++) {
        int c = c0 + ty + yy * 8;
        int rc = (MODE == 0) ? c
               : (MODE == 1) ? ((c < I) ? 2 * c : 2 * (c - I) + 1)
               : (MODE == 2) ? 2 * c : 2 * c + 1;
        d[(size_t)rc * R + r0 + tx] = (bf16_t)t[tx][ty + yy * 8];
    }
}

// ------------------------------- router -----------------------------------

__global__ __launch_bounds__(256) void k_router(const float* __restrict__ x,
                                                const float* __restrict__ gw,
                                                const float* __restrict__ eb,
                                                float* __restrict__ out_idx,
                                                float* __restrict__ out_scores,
                                                float* __restrict__ topk_w,
                                                int* __restrict__ tok_expert,
                                                int* __restrict__ counts) {
    int t = blockIdx.x;
    int tid = threadIdx.x;
    int e = tid & 31, part = tid >> 5;         // 8 parts x 256 d each
    const float* xr = x + (size_t)t * D;
    float partial = 0.f;
    int d0 = part * 256;
    for (int d = d0; d < d0 + 256; d++)
        partial += xr[d] * gw[(size_t)d * E + e];

    __shared__ float red[8][32];
    __shared__ float sc[32], sfr[32];
    red[part][e] = partial;
    __syncthreads();
    if (tid < 32) {
        float l = 0.f;
#pragma unroll
        for (int p = 0; p < 8; p++) l += red[p][tid];
        float s = 1.f / (1.f + expf(-l));
        sc[tid] = s;
        sfr[tid] = s + eb[tid];
        out_scores[(size_t)t * E + tid] = s;
    }
    __syncthreads();
    if (tid == 0) {
        float gs[8];
#pragma unroll
        for (int g = 0; g < 8; g++) {
            float m1 = -1e30f, m2 = -1e30f;
#pragma unroll
            for (int i = 0; i < 4; i++) {
                float v = sfr[g * 4 + i];
                if (v > m1) { m2 = m1; m1 = v; } else if (v > m2) m2 = v;
            }
            gs[g] = m1 + m2;
        }
        bool gsel[8] = {false, false, false, false, false, false, false, false};
        for (int it = 0; it < 4; it++) {
            int bi = -1; float bv = -1e30f;
            for (int g = 0; g < 8; g++)
                if (!gsel[g] && gs[g] > bv) { bv = gs[g]; bi = g; }
            gsel[bi] = true;
        }
        float masked[32];
        for (int i = 0; i < 32; i++) masked[i] = gsel[i >> 2] ? sfr[i] : -1e30f;
        int idx[TK]; float w[TK]; float wsum = 0.f;
        for (int k = 0; k < TK; k++) {
            int bi = 0; float bv = -1e30f;
            for (int i = 0; i < 32; i++)
                if (masked[i] > bv) { bv = masked[i]; bi = i; }
            masked[bi] = -1e30f;
            idx[k] = bi; w[k] = sc[bi]; wsum += w[k];
        }
        float inv = RSCALE / (wsum + 1e-20f);
        for (int k = 0; k < TK; k++) {
            out_idx[(size_t)t * TK + k] = (float)idx[k];
            topk_w[(size_t)t * TK + k] = w[k] * inv;
            tok_expert[(size_t)t * TK + k] = idx[k];
            atomicAdd(&counts[idx[k]], 1);
        }
    }
}

__global__ __launch_bounds__(64) void k_offsets(const int* __restrict__ counts,
                                                int* __restrict__ offs,
                                                int4* __restrict__ ttbl,
                                                int* __restrict__ ntl) {
    if (threadIdx.x != 0) return;
    int off = 0, nt = 0;
    for (int e = 0; e < E; e++) {
        offs[e] = off;
        int c = counts[e];
        for (int r = 0; r < c; r += TM) {
            ttbl[nt] = make_int4(off + r, min(TM, c - r), e, 0);
            nt++;
        }
        off += c;
    }
    offs[E] = off;
    *ntl = nt;
}

__global__ __launch_bounds__(256) void k_scatter(const int* __restrict__ tok_expert,
                                                 const int* __restrict__ offs,
                                                 int* __restrict__ cursors,
                                                 int* __restrict__ slot_token,
                                                 int* __restrict__ slot_inv) {
    int i = blockIdx.x * 256 + threadIdx.x;
    if (i >= NK) return;
    int e = tok_expert[i];
    int pos = offs[e] + atomicAdd(&cursors[e], 1);
    slot_token[pos] = i >> 3;   // TK = 8
    slot_inv[i] = pos;
}

// --------------------- 256x256 8-phase pipelined GEMM ----------------------
// 512 threads = 8 waves (2M x 4N); per-wave C = 128 rows x 64 cols.
// LDS 128 KiB: 2 buffers x (A[256][64] + B[256][64]) bf16, XOR-swizzled.
//
// R12 = R10 dataflow with in-phase refill interleave (WAR-safe):
//   aF single set; refill of aF[m] placed right after its last consuming
//   MFMA (in-order issue => MFMA reads old aF at issue; ds_read writes at
//   completion => no race).  sched_group_barrier pins per-phase emission:
//   [pre-reads] [GL16 x2] 4x{MFMA x4, DS_READ x2}.
// Stage plan + vmcnt(4)/phase protocol identical to R10:
//   P1:A1(rnd1,t1)  P2:A0(rnd0,t0+2)  P3:B0(h0,t0+2)  P4:B0(h1,t0+2)
//   P5:A0(rnd1,t0+2) P6:A1(rnd0,t1+2) P7:B1(h0,t1+2)  P8:B1(h1,t1+2)
//   ops@q published at end q+2; all read deadlines hold; stages land >= 2
//   phases after their region's last read-issue (drained by the consuming
//   MFMA's lgkm wait in the intervening phase) — WAR-safe.

#define SCB() __builtin_amdgcn_sched_barrier(0)
#define SG(m, n) __builtin_amdgcn_sched_group_barrier(m, n, 0)
// per-phase SGB tails (region = barrier..barrier):
#define SG_PLAIN() do { SG(0x30, 2); SG(0x8, 16); } while (0)
#define SG_PRE()   do { SG(0x100, 4); SG(0x30, 2); SG(0x8, 16); } while (0)
#define SG_RF()    do { SG(0x30, 2); SG(0x8, 4); SG(0x100, 2); SG(0x8, 4); \
    SG(0x100, 2); SG(0x8, 4); SG(0x100, 2); SG(0x8, 4); SG(0x100, 2); } while (0)
#define SG_PRERF() do { SG(0x100, 4); SG(0x30, 2); SG(0x8, 4); SG(0x100, 2); \
    SG(0x8, 4); SG(0x100, 2); SG(0x8, 4); SG(0x100, 2); SG(0x8, 4); SG(0x100, 2); } while (0)

#define PEND() do { asm volatile("s_waitcnt vmcnt(4)" ::: "memory"); \
    __builtin_amdgcn_s_barrier(); SCB(); } while (0)

// A stage unit (b, rnd): rows rnd*64..+63 and 128+rnd*64..+63
#define SA2(b, rnd, k0) do { \
    GL16(gA[0][rnd] + (k0), smb + (b) * 65536 + (rnd) * 8192 + w * 1024); \
    GL16(gA[1][rnd] + (k0), smb + (b) * 65536 + 16384 + (rnd) * 8192 + w * 1024); } while (0)

// B stage unit (b, h): cols h*128..+127
#define SB(b, h, k0) do { \
    GL16(gB[h][0] + (k0), smb + (b) * 65536 + 32768 + (h) * 16384 + w * 1024); \
    GL16(gB[h][1] + (k0), smb + (b) * 65536 + 32768 + (h) * 16384 + 8192 + w * 1024); } while (0)

#define LDA(b, mh) do { _Pragma("unroll") for (int m_ = 0; m_ < 4; m_++) { \
    aF[m_][0] = *(const bf16x8*)(smb + (b) * 65536 + wm * 16384 + (mh) * 8192 + m_ * 2048 + lofs0); \
    aF[m_][1] = *(const bf16x8*)(smb + (b) * 65536 + wm * 16384 + (mh) * 8192 + m_ * 2048 + lofs1); } } while (0)

#define LDB(dst, b, nh) do { _Pragma("unroll") for (int n_ = 0; n_ < 2; n_++) { \
    dst[n_][0] = *(const bf16x8*)(smb + (b) * 65536 + 32768 + wn * 8192 + (nh) * 4096 + n_ * 2048 + lofs0); \
    dst[n_][1] = *(const bf16x8*)(smb + (b) * 65536 + 32768 + wn * 8192 + (nh) * 4096 + n_ * 2048 + lofs1); } } while (0)

// plain MFMA cluster (m-major)
#define MMA(bv, MH, NH) do { \
    __builtin_amdgcn_s_setprio(1); \
    _Pragma("unroll") for (int m_ = 0; m_ < 4; m_++) \
    _Pragma("unroll") for (int n_ = 0; n_ < 2; n_++) { \
    acc[(MH) * 4 + m_][(NH) * 2 + n_] = __builtin_amdgcn_mfma_f32_16x16x32_bf16( \
        aF[m_][0], bv[n_][0], acc[(MH) * 4 + m_][(NH) * 2 + n_], 0, 0, 0); \
    acc[(MH) * 4 + m_][(NH) * 2 + n_] = __builtin_amdgcn_mfma_f32_16x16x32_bf16( \
        aF[m_][1], bv[n_][1], acc[(MH) * 4 + m_][(NH) * 2 + n_], 0, 0, 0); } \
    __builtin_amdgcn_s_setprio(0); } while (0)

// MFMA cluster with per-m aF refill from (rb, rmh), WAR-safe interleave
#define MMARF(bv, MH, NH, rb, rmh) do { \
    __builtin_amdgcn_s_setprio(1); \
    _Pragma("unroll") for (int m_ = 0; m_ < 4; m_++) { \
    _Pragma("unroll") for (int n_ = 0; n_ < 2; n_++) { \
    acc[(MH) * 4 + m_][(NH) * 2 + n_] = __builtin_amdgcn_mfma_f32_16x16x32_bf16( \
        aF[m_][0], bv[n_][0], acc[(MH) * 4 + m_][(NH) * 2 + n_], 0, 0, 0); \
    acc[(MH) * 4 + m_][(NH) * 2 + n_] = __builtin_amdgcn_mfma_f32_16x16x32_bf16( \
        aF[m_][1], bv[n_][1], acc[(MH) * 4 + m_][(NH) * 2 + n_], 0, 0, 0); } \
    aF[m_][0] = *(const bf16x8*)(smb + (rb) * 65536 + wm * 16384 + (rmh) * 8192 + m_ * 2048 + lofs0); \
    aF[m_][1] = *(const bf16x8*)(smb + (rb) * 65536 + wm * 16384 + (rmh) * 8192 + m_ * 2048 + lofs1); } \
    __builtin_amdgcn_s_setprio(0); } while (0)

template <bool EXPERT, bool GATHER, int EPI>
__global__ __launch_bounds__(512, 2) void k_mm8(const bf16_t* __restrict__ A,
                                                const bf16_t* __restrict__ Bt,
                                                int K, size_t estride,
                                                const int* __restrict__ slot_token,
                                                const int4* __restrict__ ttbl,
                                                const int* __restrict__ ntl,
                                                void* __restrict__ C, int ldc) {
    // XCD-chunked swizzle (grid.y divisible by 8)
    int L = (int)blockIdx.y * 8 + (int)blockIdx.x;
    int xcd = L & 7, k = L >> 3;
    int per = (int)gridDim.y >> 3;
    int ty = xcd * per + (k >> 3);
    int tx = k & 7;

    int base_slot, rows, e;
    if (EXPERT) {
        if (ty >= *ntl) return;
        int4 tt = ttbl[ty];
        base_slot = tt.x; rows = tt.y; e = tt.z;
    } else {
        base_slot = ty * TM; rows = TM; e = 0;
    }
    int c0 = tx * 256;
    const bf16_t* Bw = Bt + (size_t)e * estride + (size_t)c0 * K;

    extern __shared__ char smb[];   // 128 KiB: [2][A 32K | B 32K]

    int tid = threadIdx.x, lane = tid & 63, w = tid >> 6;
    int wm = w >> 2, wn = w & 3;
    int lr = lane & 15, hi = lane >> 4;
    int rx = lr & 7;
    // swizzled ds_read lane offsets (16B chunk cb in [0,8), cb ^= row&7)
    int lofs0 = lr * 128 + ((hi ^ rx) << 4);
    int lofs1 = lr * 128 + (((4 + hi) ^ rx) << 4);

    // staging: row = h*128 + rnd*64 + tid/8; global chunk = (tid&7) ^ (row&7)
    int srow = tid >> 3;
    int cbg = (tid & 7) ^ (srow & 7);
    const bf16_t* gA[2][2]; const bf16_t* gB[2][2];
#pragma unroll
    for (int h = 0; h < 2; h++)
#pragma unroll
        for (int rnd = 0; rnd < 2; rnd++) {
            int r = h * 128 + rnd * 64 + srow;
            int ar = min(r, rows - 1);
            int tok = GATHER ? slot_token[base_slot + ar] : (base_slot + ar);
            gA[h][rnd] = A + (size_t)tok * K + cbg * 8;
            gB[h][rnd] = Bw + (size_t)r * K + cbg * 8;
        }

    f32x4 acc[8][4] = {};
    bf16x8 aF[4][2], b0[2][2], b1[2][2];

    // prologue: buf0 full (t0=0), buf1 all but A.rnd1 (staged at P1).
    SA2(0, 0, 0); SA2(0, 1, 0);
    SB(0, 0, 0); SB(0, 1, 0);
    SA2(1, 0, 64);
    SB(1, 0, 64); SB(1, 1, 64);
    asm volatile("s_waitcnt vmcnt(0)" ::: "memory");
    __builtin_amdgcn_s_barrier();
    SCB();
    LDA(0, 0); LDB(b0, 0, 0);

    int nt = K >> 6;                 // K/64, even (16 or 32)
    for (int kt = 0; kt < nt; kt += 2) {
        int k1 = (kt + 1) << 6;
        int k2 = (kt + 2 < nt) ? (kt + 2) << 6 : 0;   // wrapped, never consumed
        int k3 = (kt + 3 < nt) ? (kt + 3) << 6 : 0;
        // P1: pre-read b1<-buf0.nh1 | MFMA(aF=buf0.mh0, b0) | stage buf1.A.rnd1
        LDB(b1, 0, 1);
        SA2(1, 1, k1);
        MMA(b0, 0, 0);
        SG_PRE(); PEND();
        // P2: MFMA(aF, b1) with refill aF<-buf0.mh1 | stage buf0.A.rnd0[t0+2]
        SA2(0, 0, k2);
        MMARF(b1, 0, 1, 0, 1);
        SG_RF(); PEND();
        // P3: MFMA(aF=buf0.mh1, b0) | stage buf0.B.h0[t0+2]
        SB(0, 0, k2);
        MMA(b0, 1, 0);
        SG_PLAIN(); PEND();
        // P4: pre-read b0<-buf1.nh0 | MFMA(aF, b1) refill aF<-buf1.mh0 | stage B.h1
        LDB(b0, 1, 0);
        SB(0, 1, k2);
        MMARF(b1, 1, 1, 1, 0);
        SG_PRERF(); PEND();
        // P5: pre-read b1<-buf1.nh1 | MFMA(aF=buf1.mh0, b0) | stage buf0.A.rnd1[t0+2]
        LDB(b1, 1, 1);
        SA2(0, 1, k2);
        MMA(b0, 0, 0);
        SG_PRE(); PEND();
        // P6: MFMA(aF, b1) refill aF<-buf1.mh1 | stage buf1.A.rnd0[t1+2]
        SA2(1, 0, k3);
        MMARF(b1, 0, 1, 1, 1);
        SG_RF(); PEND();
        // P7: MFMA(aF=buf1.mh1, b0) | stage buf1.B.h0[t1+2]
        SB(1, 0, k3);
        MMA(b0, 1, 0);
        SG_PLAIN(); PEND();
        // P8: pre-read b0<-buf0'.nh0 | MFMA(aF, b1) refill aF<-buf0'.mh0 | stage B.h1
        LDB(b0, 0, 0);
        SB(1, 1, k3);
        MMARF(b1, 1, 1, 0, 0);
        SG_PRERF(); PEND();
    }

    // epilogue: C row r = wm*128 + mi*16 + hi*4 + j, col = c0 + wn*64 + f*16 + lr
#pragma unroll
    for (int mi = 0; mi < 8; mi++) {
#pragma unroll
        for (int j = 0; j < 4; j++) {
            int r = wm * 128 + mi * 16 + hi * 4 + j;
            bool valid = !EXPERT || (r < rows);
            size_t orow = (size_t)base_slot + r;
#pragma unroll
            for (int f = 0; f < 4; f++) {
                float v = acc[mi][f][j];
                int c = c0 + wn * 64 + f * 16 + lr;
                if (EPI == 0) {
                    float o = __shfl_xor(v, 1);
                    float g = (lane & 1) ? o : v;
                    float u = (lane & 1) ? v : o;
                    float sv = g / (1.f + __expf(-g)) * u;
                    if (valid && !(lane & 1))
                        ((bf16_t*)C)[orow * ldc + (c >> 1)] = (bf16_t)sv;
                } else if (EPI == 1) {
                    float o = __shfl_xor(v, 1);
                    if (valid && !(lane & 1)) {
                        bf16_t pr[2] = {(bf16_t)v, (bf16_t)o};
                        *(unsigned int*)((bf16_t*)C + orow * ldc + c) = *(unsigned int*)pr;
                    }
                } else {
                    if (valid) ((float*)C)[orow * ldc + c] = v;
                }
            }
        }
    }
}

// ------------------------------- finalize ----------------------------------
// out[tok][d] += sum_k w_k * outS[pos(tok,k)][d]   (out already = shared MLP)

__global__ __launch_bounds__(256) void k_finalize(const bf16_t* __restrict__ outS,
                                                  const int* __restrict__ slot_inv,
                                                  const float* __restrict__ tkw,
                                                  float* __restrict__ out) {
    int tok = blockIdx.x, tid = threadIdx.x;
    __shared__ int sp[TK];
    __shared__ float swt[TK];
    if (tid < TK) {
        sp[tid] = slot_inv[tok * TK + tid];
        swt[tid] = tkw[tok * TK + tid];
    }
    __syncthreads();
    int c = tid * 8;                 // 2048 / 256
    float* op = out + (size_t)tok * D + c;
    float acc[8];
    float4 o0 = *(float4*)op, o1 = *(float4*)(op + 4);
    acc[0] = o0.x; acc[1] = o0.y; acc[2] = o0.z; acc[3] = o0.w;
    acc[4] = o1.x; acc[5] = o1.y; acc[6] = o1.z; acc[7] = o1.w;
#pragma unroll
    for (int k = 0; k < TK; k++) {
        bf16x8 v = *(const bf16x8*)(outS + (size_t)sp[k] * D + c);
        float w = swt[k];
#pragma unroll
        for (int j = 0; j < 8; j++) acc[j] += w * (float)v[j];
    }
    o0 = make_float4(acc[0], acc[1], acc[2], acc[3]);
    o1 = make_float4(acc[4], acc[5], acc[6], acc[7]);
    *(float4*)op = o0;
    *(float4*)(op + 4) = o1;
}

// ------------------------------- launcher ---------------------------------

extern "C" void kernel_launch(void* const* d_in, const int* in_sizes, int n_in,
                              void* d_out, int out_size, void* d_ws, size_t ws_size,
                              hipStream_t stream) {
    const float* x  = (const float*)d_in[0];
    const float* gw = (const float*)d_in[1];
    const float* eb = (const float*)d_in[2];
    const float* gu = (const float*)d_in[3];
    const float* dn = (const float*)d_in[4];
    const float* sg = (const float*)d_in[5];
    const float* su = (const float*)d_in[6];
    const float* sd = (const float*)d_in[7];

    float* out        = (float*)d_out;
    float* out_idx    = out + (size_t)NTOK * D;
    float* out_scores = out_idx + (size_t)NTOK * TK;

    char* w = (char*)d_ws;
    auto alloc = [&](size_t bytes) {
        char* p = w;
        w += (bytes + 255) & ~(size_t)255;
        return p;
    };
    bf16_t* xb      = (bf16_t*)alloc((size_t)NTOK * D * 2);
    bf16_t* gut     = (bf16_t*)alloc((size_t)E * 2 * I * D * 2);   // [E][2I][D] interleaved
    bf16_t* dnt     = (bf16_t*)alloc((size_t)E * D * I * 2);       // [E][D][I]
    bf16_t* sh1t    = (bf16_t*)alloc((size_t)2 * I * D * 2);       // [2I][D] interleaved
    bf16_t* sdt     = (bf16_t*)alloc((size_t)D * I * 2);           // [D][I]
    bf16_t* inter   = (bf16_t*)alloc((size_t)NK * I * 2);
    bf16_t* inter_s = (bf16_t*)alloc((size_t)NTOK * I * 2);
    float*  tkw     = (float*)alloc((size_t)NK * 4);
    int*    tke     = (int*)alloc((size_t)NK * 4);
    int*    stok    = (int*)alloc((size_t)NK * 4);
    int*    sinv    = (int*)alloc((size_t)NK * 4);
    int*    counts  = (int*)alloc(E * 4);
    int*    offs    = (int*)alloc((E + 1) * 4);
    int*    curs    = (int*)alloc(E * 4);
    int4*   ttbl    = (int4*)alloc(MAX_TILES * 16);
    int*    ntl     = (int*)alloc(4);
    // outS[NK][D] bf16 (256MB) aliases gut (256MB): gut is dead after expert gemm1
    bf16_t* outS    = gut;

    if ((size_t)(w - (char*)d_ws) > ws_size) {
        k_sentinel<<<1, 64, 0, stream>>>(out);
        return;
    }

    k_zero_meta<<<1, 64, 0, stream>>>(counts, curs, ntl);
    k_convert_x<<<(NTOK * D / 8 + 255) / 256, 256, 0, stream>>>(x, xb, NTOK * D / 8);

    // weight reshapes
    k_transpose<1><<<dim3(2 * I / 32, D / 32, E), dim3(32, 8), 0, stream>>>(
        gu, gut, D, 2 * I, (size_t)D * 2 * I, (size_t)D * 2 * I);
    k_transpose<0><<<dim3(D / 32, I / 32, E), dim3(32, 8), 0, stream>>>(
        dn, dnt, I, D, (size_t)I * D, (size_t)I * D);
    k_transpose<2><<<dim3(I / 32, D / 32, 1), dim3(32, 8), 0, stream>>>(
        sg, sh1t, D, I, 0, 0);
    k_transpose<3><<<dim3(I / 32, D / 32, 1), dim3(32, 8), 0, stream>>>(
        su, sh1t, D, I, 0, 0);
    k_transpose<0><<<dim3(D / 32, I / 32, 1), dim3(32, 8), 0, stream>>>(
        sd, sdt, I, D, 0, 0);

    // routing
    k_router<<<NTOK, 256, 0, stream>>>(x, gw, eb, out_idx, out_scores, tkw, tke, counts);
    k_offsets<<<1, 64, 0, stream>>>(counts, offs, ttbl, ntl);
    k_scatter<<<NK / 256, 256, 0, stream>>>(tke, offs, curs, stok, sinv);

    constexpr size_t SMEM = 131072;
    // expert path (gemm1 must finish before outS overwrites gut)
    k_mm8<true, true, 0><<<dim3(8, MAX_TILES), 512, SMEM, stream>>>(
        xb, gut, D, (size_t)2 * I * D, stok, ttbl, ntl, inter, I);
    k_mm8<true, false, 1><<<dim3(8, MAX_TILES), 512, SMEM, stream>>>(
        inter, dnt, I, (size_t)D * I, stok, ttbl, ntl, outS, D);

    // shared path
    k_mm8<false, false, 0><<<dim3(8, NTOK / TM), 512, SMEM, stream>>>(
        xb, sh1t, D, 0, nullptr, nullptr, nullptr, inter_s, I);
    k_mm8<false, false, 2><<<dim3(8, NTOK / TM), 512, SMEM, stream>>>(
        inter_s, sdt, I, 0, nullptr, nullptr, nullptr, out, D);

    // combine
    k_finalize<<<NTOK, 256, 0, stream>>>(outS, sinv, tkw, out);
}